// Round 6
// baseline (707.060 us; speedup 1.0000x reference)
//
#include <hip/hip_runtime.h>

// LSTM I=16, H=32, B=8192, T=512, fp32 — MFMA, producer/consumer wave split.
// (Resubmission: round-5 bench was an infra failure — same signature as
// round 2, which passed on identical resubmission. Source re-audited:
// barriers uniform, handoffs race-free, resources within limits.)
//
// Block = 1024 threads (16 waves) per 16 batch rows; grid 512 -> 2048
// threads/CU = 8 waves/SIMD (hardware max; round-3 structure had 4).
//
//   consumers (waves 0-7): gate-block recurrence. Phase A: C = gx[t] (LDS,
//     f32, exact) + 3-deep hh MFMA chain -> publish gbuf. Phase B: gather 4
//     gates of the ONE owned element, cell update, write h planes.
//   producers (waves 8-15): phase A: gx(t+1) = bias + x[t+1]@W_ih (2 MFMAs,
//     recurrence-independent, one step ahead). Phase B: publish gx ring.
//     Waves 8-11 additionally stage split-x (global f32 -> bf16 hi/lo plane).
//
// Barriers at COMMON program points (wave-uniform role branch inside each
// phase). Handoff audit (write -> barrier(s) -> read):
//   gx[p^1]  written B(t)  -> b2 -> read A(t+1)                 [ring parity]
//   xs[p]    written B(t)  -> b2 -> read A(t+1) (producers)     [x(t+2)]
//   gbuf     written A(t)  -> b1 -> read B(t); rewritten A(t+1) after b2
//   hl[p^1]  written B(t)  -> b2 -> read A(t+1)
//
// Round-4 lesson applied: ih MFMAs inside the consumer wave serialized behind
// the phase-B gather (regressed 397->412); moving them to separate waves
// keeps consumer phases short and lets the scheduler overlap them.
// Round-4 lesson 2: SQ_LDS_BANK_CONFLICT is inherent 2-way wave64 aliasing
// (free per m136) — not worth optimizing further.
//
// Precision: split-bf16, order identical to round 3/4 (bit-identical result):
// gates = bias + (x1+x2)@W1 + (x1+x2)@W2 (via exact f32 LDS handoff)
//       + h1@W1 + h2@W1 + h1@W2   (h2@W2 dropped, < 1e-4).
// MFMA 16x16x32 bf16 mapping: A: lane(m,q) holds A[m][8q+j]; B: lane(n,q)
// holds B[8q+j][n]; C/D: lane holds D[4q+reg][n]  (m89/m92-verified family).

typedef float f4 __attribute__((ext_vector_type(4)));
typedef __bf16 bf8v __attribute__((ext_vector_type(8)));

constexpr int ISZ = 16, HSZ = 32, TT = 512, BB = 8192;
constexpr int HSTR = 72;  // bf16/row: [h1(32)|h2(32)] + 8 pad (b128 reads at floor)
constexpr int XSTR = 40;  // bf16/row: [x1(16)|x2(16)] + 8 pad
constexpr int GSTR = 34;  // f32/row: publish/gather/C-load all 2-way (free)

#define MFMA32(a, b, c) __builtin_amdgcn_mfma_f32_16x16x32_bf16((a), (b), (c), 0, 0, 0)

__device__ __forceinline__ float fsig(float x) {
  return __builtin_amdgcn_rcpf(1.0f + __builtin_amdgcn_exp2f(-1.44269504f * x));
}

// split 8 fp32 -> hi/lo bf16 fragments (RNE split: v = hi + lo + O(2^-16 v))
__device__ __forceinline__ void split8(const float* v, bf8v& hi, bf8v& lo) {
#pragma unroll
  for (int i = 0; i < 8; ++i) {
    const __bf16 h = (__bf16)v[i];
    hi[i] = h;
    lo[i] = (__bf16)(v[i] - (float)h);
  }
}

__global__ __launch_bounds__(1024, 8) void lstm_mfma(
    const float* __restrict__ x, const float* __restrict__ W_ih,
    const float* __restrict__ W_hh, const float* __restrict__ b_ih,
    const float* __restrict__ b_hh, const float* __restrict__ W_fc,
    const float* __restrict__ b_fc, float* __restrict__ out) {
  __shared__ __align__(16) __bf16 hl[2][16][HSTR];       // 4608 B
  __shared__ __align__(16) __bf16 xs[2][16][XSTR];       // 2560 B
  __shared__ __align__(16) float gbuf[4][16][GSTR];      // 8704 B
  __shared__ __align__(16) float gx[2][4][16][GSTR];     // 17408 B (ih ring)

  const int tid = threadIdx.x;
  const int wv = tid >> 6;            // 0..15
  const bool isProd = wv >= 8;        // producer waves 8..15
  const int gw = wv & 3;              // gate (i,f,g,o) of this wave's N-block
  const int uh = (wv >> 2) & 1;       // unit half
  const int L = tid & 63;
  const int m = L & 15;               // M (batch row) for A/C; N (unit) for B
  const int q = L >> 4;               // quad
  const int row0 = blockIdx.x * 16;
  const int uw = uh * 16 + m;         // unit column of this wave's block
  const int j = gw * 32 + uw;         // gate row in the 4H dim

  // consumer-owned cell element (512 elements over waves 0..7)
  const int eR = (wv & 7) * 2 + (L >> 5);  // batch row 0..15
  const int eu = L & 31;                   // unit 0..31

  // x staging duty: waves 8..11 (wave-uniform), 256 lanes
  const bool doStage = (wv >= 8) && (wv < 12);
  const int st = tid & 255;
  const int xr = st >> 4, xi = st & 15;
  const float* xbase = x + (size_t)(row0 + xr) * TT * ISZ + xi;

  // ---- per-role weight fragments (loaded once) ----
  bf8v wA1, wA2;        // consumer: hh hi/lo ; producer: ih hi/lo
  f4 biasv = (f4){0.0f, 0.0f, 0.0f, 0.0f};
  if (!isProd) {
    float wh[8];
    *(f4*)&wh[0] = *(const f4*)(W_hh + j * HSZ + 8 * q);
    *(f4*)&wh[4] = *(const f4*)(W_hh + j * HSZ + 8 * q + 4);
    split8(wh, wA1, wA2);
  } else {
    float wi[8];
    const int k8 = (q & 1) * 8;  // B rows k>=16 wrap to W_ih k-16 ([x1|x2] pack)
    *(f4*)&wi[0] = *(const f4*)(W_ih + j * ISZ + k8);
    *(f4*)&wi[4] = *(const f4*)(W_ih + j * ISZ + k8 + 4);
    split8(wi, wA1, wA2);
    const float bb = b_ih[j] + b_hh[j];
    biasv = (f4){bb, bb, bb, bb};
  }

  // ---- prologue: zero h; stage xs[0]=x[0], xs[1]=x[1]; gx[0]=bias+x0@Wih ----
  for (int i = tid; i < 2 * 16 * HSTR; i += 1024) ((__bf16*)hl)[i] = (__bf16)0.0f;
  if (doStage) {
    const float v0 = xbase[0];
    const __bf16 h0 = (__bf16)v0;
    xs[0][xr][xi] = h0;
    xs[0][xr][16 + xi] = (__bf16)(v0 - (float)h0);
    const float v1 = xbase[ISZ];
    const __bf16 h1 = (__bf16)v1;
    xs[1][xr][xi] = h1;
    xs[1][xr][16 + xi] = (__bf16)(v1 - (float)h1);
  }
  __syncthreads();
  if (isProd) {
    const bf8v ax = *(const bf8v*)&xs[0][m][8 * q];
    f4 a = MFMA32(ax, wA1, biasv);
    a = MFMA32(ax, wA2, a);
#pragma unroll
    for (int r = 0; r < 4; ++r) gx[0][gw][q * 4 + r][uw] = a[r];
  }
  __syncthreads();
  // invariants at top of t: hl[t&1]=h(t); gx[t&1]=bias+x[t]@Wih; xs[(t+1)&1]=x[t+1]

  float cst = 0.0f;    // consumer: cell state of the ONE owned element
  float xnext = 0.0f;  // stager: raw x[t+2]
  f4 pacc;             // producer: gx(t+1) between phases

  for (int t = 0; t < TT; ++t) {
    const int p = t & 1;
    // ================= phase A =================
    if (!isProd) {
      f4 c;
#pragma unroll
      for (int r = 0; r < 4; ++r) c[r] = gx[p][gw][q * 4 + r][uw];  // exact f32
      const bf8v ah1 = *(const bf8v*)&hl[p][m][8 * q];
      const bf8v ah2 = *(const bf8v*)&hl[p][m][32 + 8 * q];
      f4 a = MFMA32(ah1, wA1, c);   // h1@W1
      a = MFMA32(ah2, wA1, a);      // h2@W1
      a = MFMA32(ah1, wA2, a);      // h1@W2
#pragma unroll
      for (int r = 0; r < 4; ++r) gbuf[gw][q * 4 + r][uw] = a[r];
    } else {
      const bf8v ax = *(const bf8v*)&xs[p ^ 1][m][8 * q];  // x[t+1]
      pacc = MFMA32(ax, wA1, biasv);
      pacc = MFMA32(ax, wA2, pacc);
      if (doStage) {
        const int tl = (t + 2 < TT) ? t + 2 : TT - 1;
        xnext = xbase[(size_t)tl * ISZ];  // issue early; used after b1
      }
    }
    __syncthreads();  // b1: gbuf ready
    // ================= phase B =================
    if (!isProd) {
      const float vi = gbuf[0][eR][eu];
      const float vf = gbuf[1][eR][eu];
      const float vg = gbuf[2][eR][eu];
      const float vo = gbuf[3][eR][eu];
      const float ig = fsig(vi);
      const float fg = fsig(vf);
      const float gv = 2.0f * fsig(2.0f * vg) - 1.0f;  // tanh(g)
      const float og = fsig(vo);
      const float cc = fg * cst + ig * gv;
      cst = cc;
      const float th = 2.0f * fsig(2.0f * cc) - 1.0f;  // tanh(c)
      const float h = og * th;
      const __bf16 h1 = (__bf16)h;
      hl[p ^ 1][eR][eu] = h1;
      hl[p ^ 1][eR][32 + eu] = (__bf16)(h - (float)h1);
    } else {
#pragma unroll
      for (int r = 0; r < 4; ++r) gx[p ^ 1][gw][q * 4 + r][uw] = pacc[r];
      if (doStage) {
        const __bf16 xh = (__bf16)xnext;  // stage x[t+2] into xs[t&1]
        xs[p][xr][xi] = xh;
        xs[p][xr][16 + xi] = (__bf16)(xnext - (float)xh);
      }
    }
    __syncthreads();  // b2: h(t+1), gx(t+1), xs(t+2) ready
  }

  // ---- epilogue: out[row] = sum_u h[row][u]*W_fc[u] + b_fc ----
  // final h (t=TT) is in hl[0] (TT even)
  if (tid < 16) {
    float s = b_fc[0];
#pragma unroll 8
    for (int uu = 0; uu < HSZ; ++uu) {
      const float h = (float)hl[0][tid][uu] + (float)hl[0][tid][32 + uu];
      s += h * W_fc[uu];
    }
    out[row0 + tid] = s;
  }
}

extern "C" void kernel_launch(void* const* d_in, const int* in_sizes, int n_in,
                              void* d_out, int out_size, void* d_ws, size_t ws_size,
                              hipStream_t stream) {
  const float* x    = (const float*)d_in[0];
  const float* W_ih = (const float*)d_in[1];
  const float* W_hh = (const float*)d_in[2];
  const float* b_ih = (const float*)d_in[3];
  const float* b_hh = (const float*)d_in[4];
  const float* W_fc = (const float*)d_in[5];
  const float* b_fc = (const float*)d_in[6];
  float* out = (float*)d_out;

  dim3 grid(BB / 16);    // 512 blocks = 512 row-groups
  dim3 block(1024);      // 16 waves: 8 consumer (hh+cell) + 8 producer (ih)
  lstm_mfma<<<grid, block, 0, stream>>>(x, W_ih, W_hh, b_ih, b_hh, W_fc, b_fc, out);
}

// Round 7
// 702.545 us; speedup vs baseline: 1.0064x; 1.0064x over previous
//
#include <hip/hip_runtime.h>

// LSTM I=16, H=32, B=8192, T=512, fp32 — barrier-free single-wave recurrence.
//
// Each WAVE owns 8 batch rows end-to-end: all 8 gate tiles (4 gates x 2
// unit-halves), cell update, and h storage in a private LDS slice. There is
// NO __syncthreads anywhere: intra-wave LDS is ordered by the in-order DS
// pipe (compiler-inserted lgkmcnt). 1024 waves = 1 wave/SIMD machine-wide.
//
// Lesson r1->r6: barrier-phase designs cost 1860-2290 cyc/step regardless of
// occupancy (r3: 8 waves/2 barriers = 397us; r6: 16 waves = 488us). The
// serialization is the barrier structure, not wave count. This design's
// per-step cost is pure issue: ~40 MFMA + ~120 cell VALU + misc ~ 700 cyc.
//
// M-duplication trick: A-fragments are read at row (m&7), so A rows 8-15
// duplicate rows 0-7 and D rows 8-15 are valid duplicates. Lane(m,q) then
// holds, in its OWN C-registers, the 4 gates of its owned elements:
//   rows 4*(q&1)+r, unit (q>>1)*16+m   (uh-half picked by 16 cndmasks).
// No gate-exchange buffers, no cross-lane ops.
//
// Precision: split-bf16, same terms/order as r3 (absmax 0.0009765625):
// gates = bias + (x1+x2)@W1 + (x1+x2)@W2 + h1@W1 + h2@W1 + h1@W2.
// MFMA 16x16x32 bf16 mapping (m89/m92-verified family):
//   A: lane(m=L&15, q=L>>4) holds A[m][8q+j], j=0..7
//   B: lane(n=L&15, q)      holds B[8q+j][n]
//   C/D: lane holds D[4q+reg][n]

typedef float f4 __attribute__((ext_vector_type(4)));
typedef __bf16 bf8v __attribute__((ext_vector_type(8)));

constexpr int ISZ = 16, HSZ = 32, TT = 512, BB = 8192;
constexpr int RPW = 8;    // batch rows per wave
constexpr int WPB = 4;    // waves per block (independent; no sync)
constexpr int HST = 40;   // bf16 col stride (32 + 8 pad; rows 16B-aligned)

#define MFMA32(a, b, c) __builtin_amdgcn_mfma_f32_16x16x32_bf16((a), (b), (c), 0, 0, 0)

__device__ __forceinline__ float fsig(float x) {
  return __builtin_amdgcn_rcpf(1.0f + __builtin_amdgcn_exp2f(-1.44269504f * x));
}

// split 8 fp32 -> hi/lo bf16 fragments (RNE split: v = hi + lo + O(2^-16 v))
__device__ __forceinline__ void split8(const float* v, bf8v& hi, bf8v& lo) {
#pragma unroll
  for (int i = 0; i < 8; ++i) {
    const __bf16 h = (__bf16)v[i];
    hi[i] = h;
    lo[i] = (__bf16)(v[i] - (float)h);
  }
}

__global__ __launch_bounds__(256, 1) void lstm_mfma(
    const float* __restrict__ x, const float* __restrict__ W_ih,
    const float* __restrict__ W_hh, const float* __restrict__ b_ih,
    const float* __restrict__ b_hh, const float* __restrict__ W_fc,
    const float* __restrict__ b_fc, float* __restrict__ out) {
  // per-wave private h planes: [wave][buf][plane h1/h2][row 8][40 bf16]
  __shared__ __align__(16) __bf16 hlds[WPB][2][2][RPW][HST];  // 20480 B

  const int tid = threadIdx.x;
  const int wv = tid >> 6;      // wave in block (independent group)
  const int L = tid & 63;
  const int m = L & 15;         // M index for A/C; N (unit) index for B
  const int q = L >> 4;         // quad
  const int mr = m & 7;         // duplicated source row (M-duplication)
  const int qr = q & 1;         // owned row-quad
  const int qh = q >> 1;        // owned unit-half
  const int u_own = qh * 16 + m;
  const int row0 = (blockIdx.x * WPB + wv) * RPW;

  // ---- weights: all 8 tiles (g, uh) resident in VGPRs (~136 regs) ----
  bf8v wih1[4][2], wih2[4][2], whh1[4][2], whh2[4][2];
  float bb[4][2];
#pragma unroll
  for (int g = 0; g < 4; ++g)
#pragma unroll
    for (int uh = 0; uh < 2; ++uh) {
      const int j = g * 32 + uh * 16 + m;  // gate row owned as B column n=m
      float wh[8];
      *(f4*)&wh[0] = *(const f4*)(W_hh + j * HSZ + 8 * q);
      *(f4*)&wh[4] = *(const f4*)(W_hh + j * HSZ + 8 * q + 4);
      split8(wh, whh1[g][uh], whh2[g][uh]);
      float wi[8];  // [x1|x2] pack: B rows k and k+16 both = W_ih[j][k]
      *(f4*)&wi[0] = *(const f4*)(W_ih + j * ISZ + 8 * qr);
      *(f4*)&wi[4] = *(const f4*)(W_ih + j * ISZ + 8 * qr + 4);
      split8(wi, wih1[g][uh], wih2[g][uh]);
      bb[g][uh] = b_ih[j] + b_hh[j];
    }

  // ---- zero own buf0 (h_0 = 0); wave-internal, no barrier needed ----
  {
    __bf16* z = &hlds[wv][0][0][0][0];
    for (int i = L; i < 2 * RPW * HST; i += 64) z[i] = (__bf16)0.0f;
  }

  // ---- x: lane(m,q) supplies A[m][8q+j] = x̂[m&7][...]; cols 8*qr..+7 ----
  const float* xrp = x + (size_t)(row0 + mr) * TT * ISZ + 8 * qr;
  f4 xc0 = *(const f4*)(xrp);      // t=0
  f4 xc1 = *(const f4*)(xrp + 4);

  float cst[4] = {0.0f, 0.0f, 0.0f, 0.0f};  // cell states of owned elements

  for (int t = 0; t < TT; ++t) {
    const int p = t & 1;
    // h A-fragments (duplicated rows via mr)
    const bf8v ah1 = *(const bf8v*)&hlds[wv][p][0][mr][8 * q];
    const bf8v ah2 = *(const bf8v*)&hlds[wv][p][1][mr][8 * q];

    // prefetch x(t+1)
    const int tn = (t < TT - 1) ? t + 1 : t;
    const f4 xn0 = *(const f4*)(xrp + (size_t)tn * ISZ);
    const f4 xn1 = *(const f4*)(xrp + (size_t)tn * ISZ + 4);

    // build [x1|x2] A-fragment: q<2 lanes carry hi split, q>=2 carry lo
    bf8v ax;
#pragma unroll
    for (int jj = 0; jj < 8; ++jj) {
      const float v = (jj < 4) ? xc0[jj] : xc1[jj - 4];
      const __bf16 hi = (__bf16)v;
      const __bf16 lo = (__bf16)(v - (float)hi);
      ax[jj] = (q < 2) ? hi : lo;
    }

    // 8 independent 5-MFMA chains (issue-bound, pipelined)
    f4 acc[4][2];
#pragma unroll
    for (int g = 0; g < 4; ++g)
#pragma unroll
      for (int uh = 0; uh < 2; ++uh) {
        const f4 c = (f4){bb[g][uh], bb[g][uh], bb[g][uh], bb[g][uh]};
        f4 a = MFMA32(ax, wih1[g][uh], c);   // x1@W1 + x2@W1
        a = MFMA32(ax, wih2[g][uh], a);      // x1@W2 + x2@W2
        a = MFMA32(ah1, whh1[g][uh], a);     // h1@W1
        a = MFMA32(ah2, whh1[g][uh], a);     // h2@W1
        a = MFMA32(ah1, whh2[g][uh], a);     // h1@W2
        acc[g][uh] = a;
      }
    xc0 = xn0;
    xc1 = xn1;

    // ---- cell update: lane owns (rows 4*qr+r, unit u_own), 4 elements ----
    const bool hiQ = (q >= 2);  // this lane's gates live in the uh=1 tiles
#pragma unroll
    for (int r = 0; r < 4; ++r) {
      const float vi = hiQ ? acc[0][1][r] : acc[0][0][r];
      const float vf = hiQ ? acc[1][1][r] : acc[1][0][r];
      const float vg = hiQ ? acc[2][1][r] : acc[2][0][r];
      const float vo = hiQ ? acc[3][1][r] : acc[3][0][r];
      const float ig = fsig(vi);
      const float fg = fsig(vf);
      const float gv = 2.0f * fsig(2.0f * vg) - 1.0f;  // tanh(g)
      const float og = fsig(vo);
      const float cc = fg * cst[r] + ig * gv;
      cst[r] = cc;
      const float th = 2.0f * fsig(2.0f * cc) - 1.0f;  // tanh(c)
      const float h = og * th;
      const __bf16 h1 = (__bf16)h;
      const int row = 4 * qr + r;
      hlds[wv][p ^ 1][0][row][u_own] = h1;
      hlds[wv][p ^ 1][1][row][u_own] = (__bf16)(h - (float)h1);
    }
    // no barrier: same-wave DS ops are in-order; next iter's reads of
    // buf[p^1] see these writes via compiler lgkmcnt.
  }

  // ---- epilogue: out[row] = sum_u h[row][u]*W_fc[u] + b_fc ----
  // final h (t=TT) is in buf[0] (TT even); 8 rows per wave, lanes 0..7
  if (L < RPW) {
    float s = b_fc[0];
#pragma unroll 8
    for (int uu = 0; uu < HSZ; ++uu) {
      const float h =
          (float)hlds[wv][0][0][L][uu] + (float)hlds[wv][0][1][L][uu];
      s += h * W_fc[uu];
    }
    out[row0 + L] = s;
  }
}

extern "C" void kernel_launch(void* const* d_in, const int* in_sizes, int n_in,
                              void* d_out, int out_size, void* d_ws, size_t ws_size,
                              hipStream_t stream) {
  const float* x    = (const float*)d_in[0];
  const float* W_ih = (const float*)d_in[1];
  const float* W_hh = (const float*)d_in[2];
  const float* b_ih = (const float*)d_in[3];
  const float* b_hh = (const float*)d_in[4];
  const float* W_fc = (const float*)d_in[5];
  const float* b_fc = (const float*)d_in[6];
  float* out = (float*)d_out;

  dim3 grid(BB / (RPW * WPB));  // 256 blocks
  dim3 block(64 * WPB);         // 4 independent waves per block, no sync
  lstm_mfma<<<grid, block, 0, stream>>>(x, W_ih, W_hh, b_ih, b_hh, W_fc, b_fc, out);
}